// Round 21
// baseline (141.037 us; speedup 1.0000x reference)
//
#include <hip/hip_runtime.h>

using f32x4  = __attribute__((ext_vector_type(4))) float;
using u16x8  = __attribute__((ext_vector_type(8))) unsigned short;
using u16x4  = __attribute__((ext_vector_type(4))) unsigned short;
using bf16x8 = __attribute__((ext_vector_type(8))) __bf16;

__device__ __forceinline__ unsigned short f2bf(float f){
  return __builtin_bit_cast(unsigned short, (__bf16)f);   // 1-op RNE cvt
}
__device__ __forceinline__ float bf2f(unsigned short h){
  return __builtin_bit_cast(float, ((unsigned int)h) << 16);
}
__device__ __forceinline__ unsigned short f2h(float f){
  return __builtin_bit_cast(unsigned short, (_Float16)f);
}
__device__ __forceinline__ float h2f(unsigned short h){
  return (float)__builtin_bit_cast(_Float16, h);
}
__device__ __forceinline__ f32x4 mfma_bf16(u16x8 a, u16x8 b, f32x4 c){
  return __builtin_amdgcn_mfma_f32_16x16x32_bf16(
      __builtin_bit_cast(bf16x8, a), __builtin_bit_cast(bf16x8, b), c, 0, 0, 0);
}
__device__ __forceinline__ float fast_sigmoid(float x){
  return __builtin_amdgcn_rcpf(1.0f + __builtin_amdgcn_exp2f(-1.44269504f * x));
}

constexpr int C_  = 256;
constexpr int L_  = 64;
constexpr int CHW = C_ * 64;   // 16384

// LDS operand layout (bf16/fp16, 256 c x 16 p): el(c,p) = ((c>>3)*16 + p)*8 + (c&7)
// B-fragment (kc, lane): b128 at kc*512 + (lane>>4)*128 + (lane&15)*8
// staging: b128 at (ss*16+sp)*8 ; epilogue rows ro..ro+3: b64 at
// ((ro>>3)*16 + m)*8 + (ro&7)

// Raw barrier: LDS ops drained, global prefetch loads stay in flight
#define BAR_LDS() do {                                        \
    asm volatile("s_waitcnt lgkmcnt(0)" ::: "memory");        \
    __builtin_amdgcn_s_barrier();                             \
    asm volatile("" ::: "memory");                            \
  } while (0)

// R21 = R20 (85.2 us champion) + MID-STEP BARRIER (anti-phase ping-pong):
//   Phase A: P {sf/zi/k reads -> 32 MFMA}        | G {staging commit+issue, zf reads}
//   --- mid barrier ---
//   Phase B: P {blend, s_l write, staging+issue} | G {32 MFMA -> sigmoid -> k write}
//   --- end barrier ---
// Each phase has exactly ONE role on the matrix pipe and the other on
// memory/VALU: forced overlap instead of scheduler-arbitrated convoy.

__global__ __launch_bounds__(512, 2)
void kalman_kernel(const float* __restrict__ z,  const float* __restrict__ Wg,
                   const float* __restrict__ bg, const float* __restrict__ Wp,
                   const float* __restrict__ bp, float* __restrict__ out)
{
  __shared__ unsigned short zbuf[4][4096];   // z ring (2-step prefetch depth)
  __shared__ unsigned short sbuf[2][4096];   // state ping-pong (bf16)
  __shared__ unsigned short kbuf[2][4096];   // gain k ping-pong (fp16)

  // XCD swizzle: siblings (same b, q=0..3) share an XCD's L2
  const int lx  = (int)blockIdx.x;
  const int xcd = lx & 7;
  const int loc = lx >> 3;
  const int b   = xcd + 8 * (loc >> 2);
  const int q   = loc & 3;

  const int t    = (int)threadIdx.x;
  const int lane = t & 63;
  const int wv   = t >> 6;
  const int role = wv >> 2;           // 0 = P (predict+blend), 1 = G (gain, 1 step ahead)
  const int rw   = wv & 3;            // owns M-tiles rw*4 .. rw*4+3
  const int m    = lane & 15;
  const int g    = lane >> 4;

  const float* zg = z + (size_t)b * L_ * CHW + q * 16;

  // ---- weights for THIS role only: 4 M-tiles x 8 K-chunks ----
  const float* Wsel = (role == 0) ? Wp : Wg;
  const float* bsrc = (role == 0) ? bp : bg;
  u16x8 wf[4][8];
  f32x4 bsel[4];
  #pragma unroll
  for (int mi = 0; mi < 4; ++mi){
    const int mt = rw * 4 + mi;
    const float* src = Wsel + (size_t)(mt * 16 + m) * 256 + g * 8;
    #pragma unroll
    for (int kc = 0; kc < 8; ++kc){
      f32x4 a0 = *(const f32x4*)(src + kc * 32);
      f32x4 a1 = *(const f32x4*)(src + kc * 32 + 4);
      #pragma unroll
      for (int j = 0; j < 4; ++j){
        wf[mi][kc][j]     = f2bf(a0[j]);
        wf[mi][kc][j + 4] = f2bf(a1[j]);
      }
    }
    bsel[mi] = *(const f32x4*)(bsrc + mt * 16 + g * 4);
  }

  // staging ids: thread t stages rows ss*8..+7 at pixel sp
  const int sp = t & 15;
  const int ss = t >> 4;
  const float* st_src = zg + ss * 8 * 64 + sp;
  const int st_dst = (ss * 16 + sp) * 8;
  const int boff   = g * 128 + m * 8;

  // ---- prologue: z0 -> sbuf[0], z1 -> zbuf[1], z2 -> zbuf[2]; issue z3 ----
  {
    float v0[8], v1[8], v2[8];
    #pragma unroll
    for (int j = 0; j < 8; ++j) v0[j] = st_src[j * 64];
    #pragma unroll
    for (int j = 0; j < 8; ++j) v1[j] = st_src[CHW + j * 64];
    #pragma unroll
    for (int j = 0; j < 8; ++j) v2[j] = st_src[2 * CHW + j * 64];
    u16x8 u0, u1, u2;
    #pragma unroll
    for (int j = 0; j < 8; ++j){ u0[j] = f2bf(v0[j]); u1[j] = f2bf(v1[j]); u2[j] = f2bf(v2[j]); }
    *(u16x8*)(&sbuf[0][st_dst]) = u0;
    *(u16x8*)(&zbuf[1][st_dst]) = u1;
    *(u16x8*)(&zbuf[2][st_dst]) = u2;
  }
  float pf[8];
  const float* pfp = st_src + 3 * (size_t)CHW;   // z3
  #pragma unroll
  for (int j = 0; j < 8; ++j) pf[j] = pfp[j * 64];
  pfp += CHW;                                    // next issue: z4
  __syncthreads();

  // k_1 from z_1 (G-waves only)
  if (role == 1){
    u16x8 zf[8];
    #pragma unroll
    for (int kc = 0; kc < 8; ++kc) zf[kc] = *(const u16x8*)(&zbuf[1][kc * 512 + boff]);
    f32x4 gl[4] = {bsel[0], bsel[1], bsel[2], bsel[3]};
    #pragma unroll
    for (int kc = 0; kc < 8; ++kc)
      #pragma unroll
      for (int mi = 0; mi < 4; ++mi)
        gl[mi] = mfma_bf16(wf[mi][kc], zf[kc], gl[mi]);
    #pragma unroll
    for (int mi = 0; mi < 4; ++mi){
      const int ro = (rw * 4 + mi) * 16 + g * 4;
      const int el = ((ro >> 3) * 16 + m) * 8 + (ro & 7);
      u16x4 kk;
      #pragma unroll
      for (int r = 0; r < 4; ++r) kk[r] = f2h(fast_sigmoid(gl[mi][r]));
      *(u16x4*)(&kbuf[1][el]) = kk;
    }
  }
  __syncthreads();

  for (int l = 1; l < 63; ++l){
    // per-iteration register state spanning the mid-barrier
    u16x8 sf[8], zf[8];
    u16x4 zi4[4], k4[4];
    f32x4 zpA[4], zpB[4];

    // ================= Phase A =================
    if (role == 0){
      // P: reads + 32 MFMA (sole owner of the matrix pipe this phase)
      const unsigned short* sb  = sbuf[(l - 1) & 1];
      const unsigned short* zbl = zbuf[l & 3];
      const unsigned short* kb  = kbuf[l & 1];

      #pragma unroll
      for (int kc = 0; kc < 8; ++kc) sf[kc] = *(const u16x8*)(sb + kc * 512 + boff);
      #pragma unroll
      for (int mi = 0; mi < 4; ++mi){
        const int ro = (rw * 4 + mi) * 16 + g * 4;
        const int el = ((ro >> 3) * 16 + m) * 8 + (ro & 7);
        zi4[mi] = *(const u16x4*)(zbl + el);
        k4[mi]  = *(const u16x4*)(kb + el);
      }

      #pragma unroll
      for (int mi = 0; mi < 4; ++mi){ zpA[mi] = bsel[mi]; zpB[mi] = f32x4{0,0,0,0}; }
      #pragma unroll
      for (int kc = 0; kc < 4; ++kc)
        #pragma unroll
        for (int mi = 0; mi < 4; ++mi){
          zpA[mi] = mfma_bf16(wf[mi][kc],     sf[kc],     zpA[mi]);
          zpB[mi] = mfma_bf16(wf[mi][kc + 4], sf[kc + 4], zpB[mi]);
        }
    } else {
      // G: memory phase — staging commit+issue, zf reads
      if (l <= 61){
        u16x8 u;
        #pragma unroll
        for (int j = 0; j < 8; ++j) u[j] = f2bf(pf[j]);
        *(u16x8*)(&zbuf[(l + 2) & 3][st_dst]) = u;
      }
      if (l <= 60){
        #pragma unroll
        for (int j = 0; j < 8; ++j) pf[j] = pfp[j * 64];
        pfp += CHW;
      }
      const unsigned short* zb = zbuf[(l + 1) & 3];
      #pragma unroll
      for (int kc = 0; kc < 8; ++kc) zf[kc] = *(const u16x8*)(zb + kc * 512 + boff);
    }

    BAR_LDS();   // ---- mid barrier: roles swap pipes ----

    // ================= Phase B =================
    if (role == 0){
      // P: VALU/memory phase — blend, s_l write, staging commit+issue
      unsigned short* sbw = sbuf[l & 1];
      #pragma unroll
      for (int mi = 0; mi < 4; ++mi){
        const int ro = (rw * 4 + mi) * 16 + g * 4;
        const int el = ((ro >> 3) * 16 + m) * 8 + (ro & 7);
        u16x4 sh;
        #pragma unroll
        for (int r = 0; r < 4; ++r){
          float zpr = zpA[mi][r] + zpB[mi][r];
          float zh  = zpr + h2f(k4[mi][r]) * (bf2f(zi4[mi][r]) - zpr);
          sh[r] = f2bf(zh);
        }
        *(u16x4*)(sbw + el) = sh;
      }
      if (l <= 61){
        u16x8 u;
        #pragma unroll
        for (int j = 0; j < 8; ++j) u[j] = f2bf(pf[j]);
        *(u16x8*)(&zbuf[(l + 2) & 3][st_dst]) = u;
      }
      if (l <= 60){
        #pragma unroll
        for (int j = 0; j < 8; ++j) pf[j] = pfp[j * 64];
        pfp += CHW;
      }
    } else {
      // G: 32 MFMA (sole owner of the matrix pipe) -> sigmoid -> k write
      f32x4 glA[4], glB[4];
      #pragma unroll
      for (int mi = 0; mi < 4; ++mi){ glA[mi] = bsel[mi]; glB[mi] = f32x4{0,0,0,0}; }
      #pragma unroll
      for (int kc = 0; kc < 4; ++kc)
        #pragma unroll
        for (int mi = 0; mi < 4; ++mi){
          glA[mi] = mfma_bf16(wf[mi][kc],     zf[kc],     glA[mi]);
          glB[mi] = mfma_bf16(wf[mi][kc + 4], zf[kc + 4], glB[mi]);
        }

      unsigned short* kw = kbuf[(l + 1) & 1];
      #pragma unroll
      for (int mi = 0; mi < 4; ++mi){
        const int ro = (rw * 4 + mi) * 16 + g * 4;
        const int el = ((ro >> 3) * 16 + m) * 8 + (ro & 7);
        u16x4 kk;
        #pragma unroll
        for (int r = 0; r < 4; ++r) kk[r] = f2h(fast_sigmoid(glA[mi][r] + glB[mi][r]));
        *(u16x4*)(kw + el) = kk;
      }
    }

    BAR_LDS();   // ---- end barrier ----
  }

  // ---- peeled final step l = 63 (P only, no barriers): out (f32) ----
  if (role == 0){
    const unsigned short* sb  = sbuf[0];          // s_62  ((63-1)&1)
    const unsigned short* zbl = zbuf[3];          // z_63  (63&3)
    const unsigned short* kb  = kbuf[1];          // k_63  (63&1)

    u16x8 sf[8];
    #pragma unroll
    for (int kc = 0; kc < 8; ++kc) sf[kc] = *(const u16x8*)(sb + kc * 512 + boff);
    u16x4 zi4[4], k4[4];
    #pragma unroll
    for (int mi = 0; mi < 4; ++mi){
      const int ro = (rw * 4 + mi) * 16 + g * 4;
      const int el = ((ro >> 3) * 16 + m) * 8 + (ro & 7);
      zi4[mi] = *(const u16x4*)(zbl + el);
      k4[mi]  = *(const u16x4*)(kb + el);
    }

    f32x4 zpA[4] = {bsel[0], bsel[1], bsel[2], bsel[3]};
    f32x4 zpB[4] = {{0,0,0,0},{0,0,0,0},{0,0,0,0},{0,0,0,0}};
    #pragma unroll
    for (int kc = 0; kc < 4; ++kc)
      #pragma unroll
      for (int mi = 0; mi < 4; ++mi){
        zpA[mi] = mfma_bf16(wf[mi][kc],     sf[kc],     zpA[mi]);
        zpB[mi] = mfma_bf16(wf[mi][kc + 4], sf[kc + 4], zpB[mi]);
      }

    #pragma unroll
    for (int mi = 0; mi < 4; ++mi){
      const int ro = (rw * 4 + mi) * 16 + g * 4;
      float* o = out + ((size_t)b * 256 + ro) * 64 + q * 16 + m;
      #pragma unroll
      for (int r = 0; r < 4; ++r){
        float zpr = zpA[mi][r] + zpB[mi][r];
        o[r * 64] = zpr + h2f(k4[mi][r]) * (bf2f(zi4[mi][r]) - zpr);
      }
    }
  }
}

extern "C" void kernel_launch(void* const* d_in, const int* in_sizes, int n_in,
                              void* d_out, int out_size, void* d_ws, size_t ws_size,
                              hipStream_t stream)
{
  const float* z  = (const float*)d_in[0];
  const float* Wg = (const float*)d_in[1];
  const float* bg = (const float*)d_in[2];
  const float* Wp = (const float*)d_in[3];
  const float* bp = (const float*)d_in[4];
  float* out = (float*)d_out;
  hipLaunchKernelGGL(kalman_kernel, dim3(256), dim3(512), 0, stream,
                     z, Wg, bg, Wp, bp, out);
}

// Round 22
// 84.842 us; speedup vs baseline: 1.6623x; 1.6623x over previous
//
#include <hip/hip_runtime.h>

using f32x4  = __attribute__((ext_vector_type(4))) float;
using u16x8  = __attribute__((ext_vector_type(8))) unsigned short;
using u16x4  = __attribute__((ext_vector_type(4))) unsigned short;
using bf16x8 = __attribute__((ext_vector_type(8))) __bf16;

__device__ __forceinline__ unsigned short f2bf(float f){
  return __builtin_bit_cast(unsigned short, (__bf16)f);   // 1-op RNE cvt
}
__device__ __forceinline__ float bf2f(unsigned short h){
  return __builtin_bit_cast(float, ((unsigned int)h) << 16);
}
__device__ __forceinline__ unsigned short f2h(float f){
  return __builtin_bit_cast(unsigned short, (_Float16)f);
}
__device__ __forceinline__ float h2f(unsigned short h){
  return (float)__builtin_bit_cast(_Float16, h);
}
__device__ __forceinline__ f32x4 mfma_bf16(u16x8 a, u16x8 b, f32x4 c){
  return __builtin_amdgcn_mfma_f32_16x16x32_bf16(
      __builtin_bit_cast(bf16x8, a), __builtin_bit_cast(bf16x8, b), c, 0, 0, 0);
}
__device__ __forceinline__ float fast_sigmoid(float x){
  return __builtin_amdgcn_rcpf(1.0f + __builtin_amdgcn_exp2f(-1.44269504f * x));
}

constexpr int C_  = 256;
constexpr int L_  = 64;
constexpr int CHW = C_ * 64;   // 16384

// LDS operand layout (bf16/fp16, 256 c x 16 p): el(c,p) = ((c>>3)*16 + p)*8 + (c&7)
// B-fragment (kc, lane): b128 at kc*512 + (lane>>4)*128 + (lane&15)*8
// staging: b128 at (ss*16+sp)*8 ; epilogue rows ro..ro+3: b64 at
// ((ro>>3)*16 + m)*8 + (ro&7)

// Raw barrier: LDS ops drained, global prefetch loads stay in flight
#define BAR_LDS() do {                                        \
    asm volatile("s_waitcnt lgkmcnt(0)" ::: "memory");        \
    __builtin_amdgcn_s_barrier();                             \
    asm volatile("" ::: "memory");                            \
  } while (0)

// FINAL (champion, R20 = 85.2 us): barrier-lockstep, role-split, phase-skewed.
//   P (waves 0-3): sf/zi/k reads -> 32 MFMA (split chains) -> blend/write s_l
//                  -> staging commit+issue (tail)
//   G (waves 4-7): zf reads issued first -> staging commit+issue -> 32 MFMA
//                  -> sigmoid -> k write
// Design ledger (measured): role-split +12% (R3); phase skew +7% (R11);
// packed casts + G-read-first +3.5% (R15); setprio REMOVAL +2.5% (R20, m190
// confirmed). Rejected by measurement: spin-flag decoupling (140-276 us),
// mid-step anti-phase barrier (141), 4/16-wave retiles (131/90.5), <16-px
// tiles (640, 8x overfetch), logit-passing (92), zi-preread (90), chain
// splits & commit moves (neutral). Structural floor: 63 serial steps x
// (LDS exchange + workgroup barrier) at 1 block/CU; per-step ~3250 cy vs
// ~1200 cy LDS + ~710 cy compute demand — residue is barrier drain +
// latency the lockstep cannot overlap at HIP level on CDNA4.

__global__ __launch_bounds__(512, 2)
void kalman_kernel(const float* __restrict__ z,  const float* __restrict__ Wg,
                   const float* __restrict__ bg, const float* __restrict__ Wp,
                   const float* __restrict__ bp, float* __restrict__ out)
{
  __shared__ unsigned short zbuf[4][4096];   // z ring (2-step prefetch depth)
  __shared__ unsigned short sbuf[2][4096];   // state ping-pong (bf16)
  __shared__ unsigned short kbuf[2][4096];   // gain k ping-pong (fp16)

  // XCD swizzle: siblings (same b, q=0..3) share an XCD's L2
  const int lx  = (int)blockIdx.x;
  const int xcd = lx & 7;
  const int loc = lx >> 3;
  const int b   = xcd + 8 * (loc >> 2);
  const int q   = loc & 3;

  const int t    = (int)threadIdx.x;
  const int lane = t & 63;
  const int wv   = t >> 6;
  const int role = wv >> 2;           // 0 = P (predict+blend), 1 = G (gain, 1 step ahead)
  const int rw   = wv & 3;            // owns M-tiles rw*4 .. rw*4+3
  const int m    = lane & 15;
  const int g    = lane >> 4;

  const float* zg = z + (size_t)b * L_ * CHW + q * 16;

  // ---- weights for THIS role only: 4 M-tiles x 8 K-chunks ----
  const float* Wsel = (role == 0) ? Wp : Wg;
  const float* bsrc = (role == 0) ? bp : bg;
  u16x8 wf[4][8];
  f32x4 bsel[4];
  #pragma unroll
  for (int mi = 0; mi < 4; ++mi){
    const int mt = rw * 4 + mi;
    const float* src = Wsel + (size_t)(mt * 16 + m) * 256 + g * 8;
    #pragma unroll
    for (int kc = 0; kc < 8; ++kc){
      f32x4 a0 = *(const f32x4*)(src + kc * 32);
      f32x4 a1 = *(const f32x4*)(src + kc * 32 + 4);
      #pragma unroll
      for (int j = 0; j < 4; ++j){
        wf[mi][kc][j]     = f2bf(a0[j]);
        wf[mi][kc][j + 4] = f2bf(a1[j]);
      }
    }
    bsel[mi] = *(const f32x4*)(bsrc + mt * 16 + g * 4);
  }

  // staging ids: thread t stages rows ss*8..+7 at pixel sp
  const int sp = t & 15;
  const int ss = t >> 4;
  const float* st_src = zg + ss * 8 * 64 + sp;
  const int st_dst = (ss * 16 + sp) * 8;
  const int boff   = g * 128 + m * 8;

  // ---- prologue: z0 -> sbuf[0], z1 -> zbuf[1], z2 -> zbuf[2]; issue z3 ----
  {
    float v0[8], v1[8], v2[8];
    #pragma unroll
    for (int j = 0; j < 8; ++j) v0[j] = st_src[j * 64];
    #pragma unroll
    for (int j = 0; j < 8; ++j) v1[j] = st_src[CHW + j * 64];
    #pragma unroll
    for (int j = 0; j < 8; ++j) v2[j] = st_src[2 * CHW + j * 64];
    u16x8 u0, u1, u2;
    #pragma unroll
    for (int j = 0; j < 8; ++j){ u0[j] = f2bf(v0[j]); u1[j] = f2bf(v1[j]); u2[j] = f2bf(v2[j]); }
    *(u16x8*)(&sbuf[0][st_dst]) = u0;
    *(u16x8*)(&zbuf[1][st_dst]) = u1;
    *(u16x8*)(&zbuf[2][st_dst]) = u2;
  }
  float pf[8];
  const float* pfp = st_src + 3 * (size_t)CHW;   // z3
  #pragma unroll
  for (int j = 0; j < 8; ++j) pf[j] = pfp[j * 64];
  pfp += CHW;                                    // next issue: z4
  __syncthreads();

  // k_1 from z_1 (G-waves only)
  if (role == 1){
    u16x8 zf[8];
    #pragma unroll
    for (int kc = 0; kc < 8; ++kc) zf[kc] = *(const u16x8*)(&zbuf[1][kc * 512 + boff]);
    f32x4 gl[4] = {bsel[0], bsel[1], bsel[2], bsel[3]};
    #pragma unroll
    for (int kc = 0; kc < 8; ++kc)
      #pragma unroll
      for (int mi = 0; mi < 4; ++mi)
        gl[mi] = mfma_bf16(wf[mi][kc], zf[kc], gl[mi]);
    #pragma unroll
    for (int mi = 0; mi < 4; ++mi){
      const int ro = (rw * 4 + mi) * 16 + g * 4;
      const int el = ((ro >> 3) * 16 + m) * 8 + (ro & 7);
      u16x4 kk;
      #pragma unroll
      for (int r = 0; r < 4; ++r) kk[r] = f2h(fast_sigmoid(gl[mi][r]));
      *(u16x4*)(&kbuf[1][el]) = kk;
    }
  }
  __syncthreads();

  for (int l = 1; l < 63; ++l){
    if (role == 0){
      // ===== P: reads -> MFMA -> blend -> staging tail =====
      const unsigned short* sb  = sbuf[(l - 1) & 1];
      const unsigned short* zbl = zbuf[l & 3];
      const unsigned short* kb  = kbuf[l & 1];
      unsigned short* sbw = sbuf[l & 1];

      u16x8 sf[8];
      #pragma unroll
      for (int kc = 0; kc < 8; ++kc) sf[kc] = *(const u16x8*)(sb + kc * 512 + boff);
      u16x4 zi4[4], k4[4];
      #pragma unroll
      for (int mi = 0; mi < 4; ++mi){
        const int ro = (rw * 4 + mi) * 16 + g * 4;
        const int el = ((ro >> 3) * 16 + m) * 8 + (ro & 7);
        zi4[mi] = *(const u16x4*)(zbl + el);
        k4[mi]  = *(const u16x4*)(kb + el);
      }

      f32x4 zpA[4] = {bsel[0], bsel[1], bsel[2], bsel[3]};
      f32x4 zpB[4] = {{0,0,0,0},{0,0,0,0},{0,0,0,0},{0,0,0,0}};
      #pragma unroll
      for (int kc = 0; kc < 4; ++kc)
        #pragma unroll
        for (int mi = 0; mi < 4; ++mi){
          zpA[mi] = mfma_bf16(wf[mi][kc],     sf[kc],     zpA[mi]);
          zpB[mi] = mfma_bf16(wf[mi][kc + 4], sf[kc + 4], zpB[mi]);
        }

      #pragma unroll
      for (int mi = 0; mi < 4; ++mi){
        const int ro = (rw * 4 + mi) * 16 + g * 4;
        const int el = ((ro >> 3) * 16 + m) * 8 + (ro & 7);
        u16x4 sh;
        #pragma unroll
        for (int r = 0; r < 4; ++r){
          float zpr = zpA[mi][r] + zpB[mi][r];
          float zh  = zpr + h2f(k4[mi][r]) * (bf2f(zi4[mi][r]) - zpr);
          sh[r] = f2bf(zh);
        }
        *(u16x4*)(sbw + el) = sh;
      }

      // staging at TAIL: commit z_{l+2}, issue z_{l+3}
      if (l <= 61){
        u16x8 u;
        #pragma unroll
        for (int j = 0; j < 8; ++j) u[j] = f2bf(pf[j]);
        *(u16x8*)(&zbuf[(l + 2) & 3][st_dst]) = u;
      }
      if (l <= 60){
        #pragma unroll
        for (int j = 0; j < 8; ++j) pf[j] = pfp[j * 64];
        pfp += CHW;
      }
    } else {
      // ===== G: zf reads first -> staging -> MFMA -> sigmoid -> k write =====
      const unsigned short* zb = zbuf[(l + 1) & 3];
      unsigned short* kw = kbuf[(l + 1) & 1];

      u16x8 zf[8];
      #pragma unroll
      for (int kc = 0; kc < 8; ++kc) zf[kc] = *(const u16x8*)(zb + kc * 512 + boff);

      if (l <= 61){
        u16x8 u;
        #pragma unroll
        for (int j = 0; j < 8; ++j) u[j] = f2bf(pf[j]);
        *(u16x8*)(&zbuf[(l + 2) & 3][st_dst]) = u;
      }
      if (l <= 60){
        #pragma unroll
        for (int j = 0; j < 8; ++j) pf[j] = pfp[j * 64];
        pfp += CHW;
      }

      f32x4 gl[4] = {bsel[0], bsel[1], bsel[2], bsel[3]};
      #pragma unroll
      for (int kc = 0; kc < 8; ++kc)
        #pragma unroll
        for (int mi = 0; mi < 4; ++mi)
          gl[mi] = mfma_bf16(wf[mi][kc], zf[kc], gl[mi]);

      #pragma unroll
      for (int mi = 0; mi < 4; ++mi){
        const int ro = (rw * 4 + mi) * 16 + g * 4;
        const int el = ((ro >> 3) * 16 + m) * 8 + (ro & 7);
        u16x4 kk;
        #pragma unroll
        for (int r = 0; r < 4; ++r) kk[r] = f2h(fast_sigmoid(gl[mi][r]));
        *(u16x4*)(kw + el) = kk;
      }
    }

    BAR_LDS();
  }

  // ---- peeled final step l = 63 (P only): out (f32) from regs ----
  if (role == 0){
    const unsigned short* sb  = sbuf[0];          // s_62  ((63-1)&1)
    const unsigned short* zbl = zbuf[3];          // z_63  (63&3)
    const unsigned short* kb  = kbuf[1];          // k_63  (63&1)

    u16x8 sf[8];
    #pragma unroll
    for (int kc = 0; kc < 8; ++kc) sf[kc] = *(const u16x8*)(sb + kc * 512 + boff);
    u16x4 zi4[4], k4[4];
    #pragma unroll
    for (int mi = 0; mi < 4; ++mi){
      const int ro = (rw * 4 + mi) * 16 + g * 4;
      const int el = ((ro >> 3) * 16 + m) * 8 + (ro & 7);
      zi4[mi] = *(const u16x4*)(zbl + el);
      k4[mi]  = *(const u16x4*)(kb + el);
    }

    f32x4 zpA[4] = {bsel[0], bsel[1], bsel[2], bsel[3]};
    f32x4 zpB[4] = {{0,0,0,0},{0,0,0,0},{0,0,0,0},{0,0,0,0}};
    #pragma unroll
    for (int kc = 0; kc < 4; ++kc)
      #pragma unroll
      for (int mi = 0; mi < 4; ++mi){
        zpA[mi] = mfma_bf16(wf[mi][kc],     sf[kc],     zpA[mi]);
        zpB[mi] = mfma_bf16(wf[mi][kc + 4], sf[kc + 4], zpB[mi]);
      }

    #pragma unroll
    for (int mi = 0; mi < 4; ++mi){
      const int ro = (rw * 4 + mi) * 16 + g * 4;
      float* o = out + ((size_t)b * 256 + ro) * 64 + q * 16 + m;
      #pragma unroll
      for (int r = 0; r < 4; ++r){
        float zpr = zpA[mi][r] + zpB[mi][r];
        o[r * 64] = zpr + h2f(k4[mi][r]) * (bf2f(zi4[mi][r]) - zpr);
      }
    }
  }
}

extern "C" void kernel_launch(void* const* d_in, const int* in_sizes, int n_in,
                              void* d_out, int out_size, void* d_ws, size_t ws_size,
                              hipStream_t stream)
{
  const float* z  = (const float*)d_in[0];
  const float* Wg = (const float*)d_in[1];
  const float* bg = (const float*)d_in[2];
  const float* Wp = (const float*)d_in[3];
  const float* bp = (const float*)d_in[4];
  float* out = (float*)d_out;
  hipLaunchKernelGGL(kalman_kernel, dim3(256), dim3(512), 0, stream,
                     z, Wg, bg, Wp, bp, out);
}